// Round 2
// baseline (736.256 us; speedup 1.0000x reference)
//
#include <hip/hip_runtime.h>
#include <hip/hip_bf16.h>
#include <cstdint>
#include <cfloat>
#include <math.h>

// Problem constants (fixed by the reference)
#define NN 4096      // rows
#define DD 256       // embedding dim
#define KC 4         // instances per class
#define NNEG 4092    // negatives per row
#define MARGIN 0.5f

// ---------------------------------------------------------------------------
// JAX threefry2x32, key = jax.random.key(42) -> (0, 42). 20 rounds.
// Partitionable mode (JAX >= 0.4.30 default): counter (hi=0, lo=i),
// bits = o0 ^ o1.
// ---------------------------------------------------------------------------
__device__ __forceinline__ uint32_t rotl32(uint32_t x, int r) {
  return (x << r) | (x >> (32 - r));
}

__device__ __forceinline__ void threefry2x32_42(uint32_t x0, uint32_t x1,
                                                uint32_t& o0, uint32_t& o1) {
  const uint32_t k0 = 0u, k1 = 42u;
  const uint32_t k2 = k0 ^ k1 ^ 0x1BD11BDAu;
  x0 += k0; x1 += k1;
#define TF_R(r) { x0 += x1; x1 = rotl32(x1, r); x1 ^= x0; }
  TF_R(13) TF_R(15) TF_R(26) TF_R(6)
  x0 += k1; x1 += k2 + 1u;
  TF_R(17) TF_R(29) TF_R(16) TF_R(24)
  x0 += k2; x1 += k0 + 2u;
  TF_R(13) TF_R(15) TF_R(26) TF_R(6)
  x0 += k0; x1 += k1 + 3u;
  TF_R(17) TF_R(29) TF_R(16) TF_R(24)
  x0 += k1; x1 += k2 + 4u;
  TF_R(13) TF_R(15) TF_R(26) TF_R(6)
  x0 += k2; x1 += k0 + 5u;
#undef TF_R
  o0 = x0; o1 = x1;
}

// gumbel noise at flat index f of the (4096, 4092) uniform draw
__device__ __forceinline__ float gumbel_at(uint32_t f) {
  uint32_t o0, o1;
  threefry2x32_42(0u, f, o0, o1);          // partitionable: counter=(0, i)
  uint32_t bits = o0 ^ o1;
  uint32_t fb = (bits >> 9) | 0x3F800000u;
  float fl = __uint_as_float(fb) - 1.0f;   // [0,1) multiples of 2^-23
  float u = fmaxf(1e-20f, fl + 1e-20f);    // (maxval-minval)==1.0f in f32
  return -logf(-logf(u));
}

// ---------------------------------------------------------------------------
// GEMM: S = X * X^T, f32, 64x64 tile, BK=64, 256 threads, 4x4 per thread
// ---------------------------------------------------------------------------
#define TS 64
#define LDSS 68   // padded LDS row stride (dwords)

__global__ __launch_bounds__(256) void gemm_sim(const float* __restrict__ X,
                                                float* __restrict__ S) {
  __shared__ float As[TS * LDSS];
  __shared__ float Bs[TS * LDSS];
  const int tid = threadIdx.x;
  const int tx = tid & 15, ty = tid >> 4;
  const int rowBase = blockIdx.y * TS, colBase = blockIdx.x * TS;
  float acc[4][4] = {};
  for (int kb = 0; kb < DD; kb += TS) {
#pragma unroll
    for (int it = 0; it < 4; ++it) {
      int idx = tid + 256 * it;            // float4 slot 0..1023
      int r = idx >> 4, c4 = idx & 15;
      float4 av = *(const float4*)(X + (size_t)(rowBase + r) * DD + kb + c4 * 4);
      float4 bv = *(const float4*)(X + (size_t)(colBase + r) * DD + kb + c4 * 4);
      *(float4*)(As + r * LDSS + c4 * 4) = av;
      *(float4*)(Bs + r * LDSS + c4 * 4) = bv;
    }
    __syncthreads();
    for (int k = 0; k < TS; k += 4) {
      float4 a[4], b[4];
#pragma unroll
      for (int i = 0; i < 4; ++i) a[i] = *(const float4*)(As + (ty + 16 * i) * LDSS + k);
#pragma unroll
      for (int j = 0; j < 4; ++j) b[j] = *(const float4*)(Bs + (tx + 16 * j) * LDSS + k);
#pragma unroll
      for (int i = 0; i < 4; ++i)
#pragma unroll
        for (int j = 0; j < 4; ++j) {
          acc[i][j] += a[i].x * b[j].x;
          acc[i][j] += a[i].y * b[j].y;
          acc[i][j] += a[i].z * b[j].z;
          acc[i][j] += a[i].w * b[j].w;
        }
    }
    __syncthreads();
  }
#pragma unroll
  for (int i = 0; i < 4; ++i)
#pragma unroll
    for (int j = 0; j < 4; ++j)
      S[(size_t)(rowBase + ty + 16 * i) * NN + colBase + tx + 16 * j] = acc[i][j];
}

// ---------------------------------------------------------------------------
// Per-row kernel: one block (256 thr) per row.
// acc[0]=sum(pos_loss+neg_loss), acc[1]=prec count, acc[2]=sum pos, acc[3]=sum neg
// ---------------------------------------------------------------------------
__global__ __launch_bounds__(256) void row_kernel(const float* __restrict__ S,
                                                  float* __restrict__ acc) {
  __shared__ float vals[NN];
  __shared__ float rs[768];
  __shared__ float rv[768];
  __shared__ float sh[16]; // 0..2 pos sorted, 3 mu, 4 inv2s2, 5..8 wave sums,
                           // 9 row neg sum, 10..13 wave sq sums
  const int row = blockIdx.x;
  const int tid = threadIdx.x;

  // load sim row
  const float4* src = (const float4*)(S + (size_t)row * NN);
#pragma unroll
  for (int it = 0; it < 4; ++it) {
    int i = tid + 256 * it;
    ((float4*)vals)[i] = src[i];
  }
  __syncthreads();

  // extract & sort the 3 positives (class block of 4, minus self)
  const int base = row & ~3;
  if (tid == 0) {
    float p[3]; int m = 0;
    for (int c = base; c < base + 4; ++c)
      if (c != row) p[m++] = vals[c];
    float t;
    if (p[0] > p[1]) { t = p[0]; p[0] = p[1]; p[1] = t; }
    if (p[1] > p[2]) { t = p[1]; p[1] = p[2]; p[2] = t; }
    if (p[0] > p[1]) { t = p[0]; p[0] = p[1]; p[1] = t; }
    sh[0] = p[0]; sh[1] = p[1]; sh[2] = p[2];
  }
  __syncthreads();
  // poison class entries (incl. diagonal) -> sink to end of ascending sort
  if (tid < 4) vals[base + tid] = INFINITY;
  __syncthreads();

  // bitonic sort, 4096 elems ascending
  for (int k = 2; k <= NN; k <<= 1) {
    for (int j = k >> 1; j > 0; j >>= 1) {
      for (int t0 = tid; t0 < NN; t0 += 256) {
        int l = t0 ^ j;
        if (l > t0) {
          float a = vals[t0], b = vals[l];
          bool up = ((t0 & k) == 0);
          if ((a > b) == up) { vals[t0] = b; vals[l] = a; }
        }
      }
      __syncthreads();
    }
  }

  // mean over first NNEG
  float s = 0.0f;
  for (int t0 = tid; t0 < NNEG; t0 += 256) s += vals[t0];
#pragma unroll
  for (int off = 32; off > 0; off >>= 1) s += __shfl_down(s, off, 64);
  if ((tid & 63) == 0) sh[5 + (tid >> 6)] = s;
  __syncthreads();
  if (tid == 0) {
    float tot = sh[5] + sh[6] + sh[7] + sh[8];
    sh[9] = tot;
    sh[3] = tot / (float)NNEG;
  }
  __syncthreads();
  const float mu = sh[3];

  // variance (two-pass, matches reference mean((x-mu)^2))
  float q = 0.0f;
  for (int t0 = tid; t0 < NNEG; t0 += 256) { float d = vals[t0] - mu; q += d * d; }
#pragma unroll
  for (int off = 32; off > 0; off >>= 1) q += __shfl_down(q, off, 64);
  if ((tid & 63) == 0) sh[10 + (tid >> 6)] = q;
  __syncthreads();
  if (tid == 0) {
    float var = (sh[10] + sh[11] + sh[12] + sh[13]) / (float)NNEG;
    float sd = sqrtf(var);
    sh[4] = 1.0f / (2.0f * sd * sd);
  }
  __syncthreads();
  const float inv2s2 = sh[4];

  // score = (v-mu)^2/(2 sd^2) + gumbel[rank]; per-thread top-3
  float s0 = -FLT_MAX, s1 = -FLT_MAX, s2 = -FLT_MAX;
  float v0 = 0.0f, v1 = 0.0f, v2 = 0.0f;
  const uint32_t fbase = (uint32_t)row * (uint32_t)NNEG;
  for (int t0 = tid; t0 < NNEG; t0 += 256) {
    float v = vals[t0];
    float d = v - mu;
    float sc = d * d * inv2s2 + gumbel_at(fbase + (uint32_t)t0);
    if (sc > s2) {
      if (sc > s1) {
        s2 = s1; v2 = v1;
        if (sc > s0) { s1 = s0; v1 = v0; s0 = sc; v0 = v; }
        else         { s1 = sc; v1 = v; }
      } else { s2 = sc; v2 = v; }
    }
  }
  rs[tid * 3 + 0] = s0; rv[tid * 3 + 0] = v0;
  rs[tid * 3 + 1] = s1; rv[tid * 3 + 1] = v1;
  rs[tid * 3 + 2] = s2; rv[tid * 3 + 2] = v2;
  __syncthreads();

  // stage 1: 64 threads each merge 4 threads' entries (12) back into slots
  if (tid < 64) {
    float g0 = -FLT_MAX, g1 = -FLT_MAX, g2 = -FLT_MAX;
    float w0 = 0.0f, w1 = 0.0f, w2 = 0.0f;
    for (int blk = 0; blk < 4; ++blk) {
      int b0 = (tid + 64 * blk) * 3;
      for (int e = 0; e < 3; ++e) {
        float sc = rs[b0 + e], v = rv[b0 + e];
        if (sc > g2) {
          if (sc > g1) {
            g2 = g1; w2 = w1;
            if (sc > g0) { g1 = g0; w1 = w0; g0 = sc; w0 = v; }
            else         { g1 = sc; w1 = v; }
          } else { g2 = sc; w2 = v; }
        }
      }
    }
    rs[tid * 3 + 0] = g0; rv[tid * 3 + 0] = w0;
    rs[tid * 3 + 1] = g1; rv[tid * 3 + 1] = w1;
    rs[tid * 3 + 2] = g2; rv[tid * 3 + 2] = w2;
  }
  __syncthreads();

  if (tid == 0) {
    float g0 = -FLT_MAX, g1 = -FLT_MAX, g2 = -FLT_MAX;
    float w0 = 0.0f, w1 = 0.0f, w2 = 0.0f;
    for (int i = 0; i < 192; ++i) {
      float sc = rs[i], v = rv[i];
      if (sc > g2) {
        if (sc > g1) {
          g2 = g1; w2 = w1;
          if (sc > g0) { g1 = g0; w1 = w0; g0 = sc; w0 = v; }
          else         { g1 = sc; w1 = v; }
        } else { g2 = sc; w2 = v; }
      }
    }
    float negmax = fmaxf(w0, fmaxf(w1, w2));
    float neg_loss = 0.04f * (log1pf(expf(50.0f * (w0 - MARGIN))) +
                              log1pf(expf(50.0f * (w1 - MARGIN))) +
                              log1pf(expf(50.0f * (w2 - MARGIN)))) / 3.0f;
    float p0 = sh[0], p1 = sh[1], p2 = sh[2];
    float pos_loss = (log1pf(expf(-2.0f * (p0 - MARGIN))) +
                      log1pf(expf(-2.0f * (p1 - MARGIN))) +
                      log1pf(expf(-2.0f * (p2 - MARGIN)))) / 3.0f;
    atomicAdd(&acc[0], pos_loss + neg_loss);
    if (p2 > negmax + 0.05f) atomicAdd(&acc[1], 1.0f);
    atomicAdd(&acc[2], p0 + p1 + p2);
    atomicAdd(&acc[3], sh[9]);
  }
}

// ---------------------------------------------------------------------------
__global__ void finalize(const float* __restrict__ acc, float* out) {
  if (threadIdx.x == 0 && blockIdx.x == 0) {
    out[0] = acc[0] / 4096.0f;                    // loss
    out[1] = acc[1] / 4096.0f;                    // prec
    out[2] = acc[2] / (4096.0f * 3.0f);           // pos_d
    out[3] = acc[3] / (4096.0f * 4092.0f);        // neg_d
  }
}

extern "C" void kernel_launch(void* const* d_in, const int* in_sizes, int n_in,
                              void* d_out, int out_size, void* d_ws, size_t ws_size,
                              hipStream_t stream) {
  (void)in_sizes; (void)n_in; (void)out_size; (void)ws_size;
  const float* X = (const float*)d_in[0];
  float* S = (float*)d_ws;                                   // 64 MB sim matrix
  float* acc = (float*)((char*)d_ws + (size_t)NN * NN * 4);  // 4 f32 accumulators
  hipMemsetAsync(acc, 0, 4 * sizeof(float), stream);
  dim3 grid(NN / TS, NN / TS);
  gemm_sim<<<grid, 256, 0, stream>>>(X, S);
  row_kernel<<<NN, 256, 0, stream>>>(S, acc);
  finalize<<<1, 64, 0, stream>>>(acc, (float*)d_out);
}

// Round 3
// 449.282 us; speedup vs baseline: 1.6387x; 1.6387x over previous
//
#include <hip/hip_runtime.h>
#include <hip/hip_bf16.h>
#include <cstdint>
#include <cfloat>
#include <math.h>

// Problem constants (fixed by the reference)
#define NN 4096      // rows
#define DD 256       // embedding dim
#define KC 4         // instances per class
#define NNEG 4092    // negatives per row
#define MARGIN 0.5f
#define NB 1024      // counting-sort buckets

// ---------------------------------------------------------------------------
// JAX threefry2x32, key = jax.random.key(42) -> (0, 42). 20 rounds.
// Partitionable mode: counter (hi=0, lo=i), bits = o0 ^ o1. (verified absmax 0)
// ---------------------------------------------------------------------------
__device__ __forceinline__ uint32_t rotl32(uint32_t x, int r) {
  return (x << r) | (x >> (32 - r));
}

__device__ __forceinline__ void threefry2x32_42(uint32_t x0, uint32_t x1,
                                                uint32_t& o0, uint32_t& o1) {
  const uint32_t k0 = 0u, k1 = 42u;
  const uint32_t k2 = k0 ^ k1 ^ 0x1BD11BDAu;
  x0 += k0; x1 += k1;
#define TF_R(r) { x0 += x1; x1 = rotl32(x1, r); x1 ^= x0; }
  TF_R(13) TF_R(15) TF_R(26) TF_R(6)
  x0 += k1; x1 += k2 + 1u;
  TF_R(17) TF_R(29) TF_R(16) TF_R(24)
  x0 += k2; x1 += k0 + 2u;
  TF_R(13) TF_R(15) TF_R(26) TF_R(6)
  x0 += k0; x1 += k1 + 3u;
  TF_R(17) TF_R(29) TF_R(16) TF_R(24)
  x0 += k1; x1 += k2 + 4u;
  TF_R(13) TF_R(15) TF_R(26) TF_R(6)
  x0 += k2; x1 += k0 + 5u;
#undef TF_R
  o0 = x0; o1 = x1;
}

__device__ __forceinline__ float gumbel_at(uint32_t f) {
  uint32_t o0, o1;
  threefry2x32_42(0u, f, o0, o1);
  uint32_t bits = o0 ^ o1;
  uint32_t fb = (bits >> 9) | 0x3F800000u;
  float fl = __uint_as_float(fb) - 1.0f;
  float u = fmaxf(1e-20f, fl + 1e-20f);
  return -logf(-logf(u));
}

// ---------------------------------------------------------------------------
// GEMM: S = X * X^T, f32, 64x64 tile (unchanged from R1 — bit-exact anchor)
// ---------------------------------------------------------------------------
#define TS 64
#define LDSS 68

__global__ __launch_bounds__(256) void gemm_sim(const float* __restrict__ X,
                                                float* __restrict__ S) {
  __shared__ float As[TS * LDSS];
  __shared__ float Bs[TS * LDSS];
  const int tid = threadIdx.x;
  const int tx = tid & 15, ty = tid >> 4;
  const int rowBase = blockIdx.y * TS, colBase = blockIdx.x * TS;
  float acc[4][4] = {};
  for (int kb = 0; kb < DD; kb += TS) {
#pragma unroll
    for (int it = 0; it < 4; ++it) {
      int idx = tid + 256 * it;
      int r = idx >> 4, c4 = idx & 15;
      float4 av = *(const float4*)(X + (size_t)(rowBase + r) * DD + kb + c4 * 4);
      float4 bv = *(const float4*)(X + (size_t)(colBase + r) * DD + kb + c4 * 4);
      *(float4*)(As + r * LDSS + c4 * 4) = av;
      *(float4*)(Bs + r * LDSS + c4 * 4) = bv;
    }
    __syncthreads();
    for (int k = 0; k < TS; k += 4) {
      float4 a[4], b[4];
#pragma unroll
      for (int i = 0; i < 4; ++i) a[i] = *(const float4*)(As + (ty + 16 * i) * LDSS + k);
#pragma unroll
      for (int j = 0; j < 4; ++j) b[j] = *(const float4*)(Bs + (tx + 16 * j) * LDSS + k);
#pragma unroll
      for (int i = 0; i < 4; ++i)
#pragma unroll
        for (int j = 0; j < 4; ++j) {
          acc[i][j] += a[i].x * b[j].x;
          acc[i][j] += a[i].y * b[j].y;
          acc[i][j] += a[i].z * b[j].z;
          acc[i][j] += a[i].w * b[j].w;
        }
    }
    __syncthreads();
  }
#pragma unroll
  for (int i = 0; i < 4; ++i)
#pragma unroll
    for (int j = 0; j < 4; ++j)
      S[(size_t)(rowBase + ty + 16 * i) * NN + colBase + tx + 16 * j] = acc[i][j];
}

// ---------------------------------------------------------------------------
// Per-row kernel v2: counting-sort ranks instead of bitonic sort.
// One block (256 thr) per row; each thread owns 16 elements (4 float4 slots).
// ---------------------------------------------------------------------------
__global__ __launch_bounds__(256) void row_kernel(const float* __restrict__ S,
                                                  float* __restrict__ acc) {
  __shared__ uint32_t hist[NB];   // per-bucket counts (preserved)
  __shared__ uint32_t offs[NB];   // excl prefix -> scatter cursor -> bucket end
  __shared__ float sval[NN];      // values scattered by bucket; later rs/rv
  __shared__ float sh[24];        // 0..2 pos sorted, 3 mu, 4 inv2s2, 5..8 wave sums,
                                  // 9 neg sum, 10..13 wave sq sums, 16..19 raw pos
  __shared__ uint32_t wtot[4];    // wave scan totals

  const int row = blockIdx.x;
  const int tid = threadIdx.x;
  const int lane = tid & 63, wid = tid >> 6;

  // zero histogram
#pragma unroll
  for (int i = 0; i < NB / 256; ++i) hist[tid + 256 * i] = 0;

  // load 16 elements (coalesced float4), capture positives, poison class block
  const float4* src = (const float4*)(S + (size_t)row * NN);
  const int pslot = row >> 2;      // float4 slot holding the class block of 4
  float vv[16];
#pragma unroll
  for (int it = 0; it < 4; ++it) {
    int slot = tid + 256 * it;
    float4 t4 = src[slot];
    if (slot == pslot) {
      sh[16] = t4.x; sh[17] = t4.y; sh[18] = t4.z; sh[19] = t4.w;
      t4.x = INFINITY; t4.y = INFINITY; t4.z = INFINITY; t4.w = INFINITY;
    }
    vv[4 * it + 0] = t4.x; vv[4 * it + 1] = t4.y;
    vv[4 * it + 2] = t4.z; vv[4 * it + 3] = t4.w;
  }
  __syncthreads();   // hist zeroed + sh[16..19] visible

  // histogram counts
#pragma unroll
  for (int e = 0; e < 16; ++e) {
    float t = fminf(fmaxf((vv[e] + 0.5f) * (float)NB, 0.0f), (float)(NB - 1));
    atomicAdd(&hist[(int)t], 1u);
  }
  __syncthreads();

  // block exclusive prefix over NB buckets (4 per thread)
  uint32_t h[4];
  uint32_t s4 = 0;
#pragma unroll
  for (int j = 0; j < 4; ++j) { h[j] = hist[tid * 4 + j]; s4 += h[j]; }
  uint32_t inc = s4;
#pragma unroll
  for (int off = 1; off < 64; off <<= 1) {
    uint32_t n = __shfl_up(inc, (unsigned)off, 64);
    if (lane >= off) inc += n;
  }
  if (lane == 63) wtot[wid] = inc;

  // tid0: sort the 3 positives meanwhile
  if (tid == 0) {
    int self = row & 3;
    float p[3]; int m = 0;
#pragma unroll
    for (int c = 0; c < 4; ++c)
      if (c != self) p[m++] = sh[16 + c];
    float t;
    if (p[0] > p[1]) { t = p[0]; p[0] = p[1]; p[1] = t; }
    if (p[1] > p[2]) { t = p[1]; p[1] = p[2]; p[2] = t; }
    if (p[0] > p[1]) { t = p[0]; p[0] = p[1]; p[1] = t; }
    sh[0] = p[0]; sh[1] = p[1]; sh[2] = p[2];
  }
  __syncthreads();
  uint32_t wbase = 0;
  for (int w = 0; w < wid; ++w) wbase += wtot[w];
  uint32_t run = wbase + inc - s4;   // exclusive scan base for my 4 buckets
#pragma unroll
  for (int j = 0; j < 4; ++j) { offs[tid * 4 + j] = run; run += h[j]; }
  __syncthreads();

  // scatter
  int slt[16];
#pragma unroll
  for (int e = 0; e < 16; ++e) {
    float v = vv[e];
    float t = fminf(fmaxf((v + 0.5f) * (float)NB, 0.0f), (float)(NB - 1));
    int b = (int)t;
    uint32_t s = atomicAdd(&offs[b], 1u);
    sval[s] = v;
    slt[e] = (int)s;
  }
  __syncthreads();

  // within-bucket rank: rank = bucket_start + #{smaller, or equal & earlier slot}
#pragma unroll
  for (int e = 0; e < 16; ++e) {
    float v = vv[e];
    float t = fminf(fmaxf((v + 0.5f) * (float)NB, 0.0f), (float)(NB - 1));
    int b = (int)t;
    uint32_t end = offs[b];
    uint32_t st = end - hist[b];
    int s = slt[e];
    int cnt = (int)st;
    for (uint32_t u = st; u < end; ++u) {
      float w = sval[u];
      if (w < v || (w == v && (int)u < s)) cnt++;
    }
    slt[e] = cnt;   // final rank in 0..4095 (infs take 4092..4095)
  }

  // mean over negatives (skip infs)
  float s = 0.0f;
#pragma unroll
  for (int e = 0; e < 16; ++e) if (vv[e] < 1e30f) s += vv[e];
#pragma unroll
  for (int off = 32; off > 0; off >>= 1) s += __shfl_down(s, off, 64);
  if (lane == 0) sh[5 + wid] = s;
  __syncthreads();
  if (tid == 0) {
    float tot = sh[5] + sh[6] + sh[7] + sh[8];
    sh[9] = tot;
    sh[3] = tot / (float)NNEG;
  }
  __syncthreads();
  const float mu = sh[3];

  // variance (two-pass)
  float q = 0.0f;
#pragma unroll
  for (int e = 0; e < 16; ++e)
    if (vv[e] < 1e30f) { float d = vv[e] - mu; q += d * d; }
#pragma unroll
  for (int off = 32; off > 0; off >>= 1) q += __shfl_down(q, off, 64);
  if (lane == 0) sh[10 + wid] = q;
  __syncthreads();
  if (tid == 0) {
    float var = (sh[10] + sh[11] + sh[12] + sh[13]) / (float)NNEG;
    float sd = sqrtf(var);
    sh[4] = 1.0f / (2.0f * sd * sd);
  }
  __syncthreads();
  const float inv2s2 = sh[4];

  // score = (v-mu)^2/(2 sd^2) + gumbel[rank]; per-thread top-3
  float* rs = sval;          // reuse scatter space for the merge arrays
  float* rv = sval + 768;
  float s0 = -FLT_MAX, s1 = -FLT_MAX, s2 = -FLT_MAX;
  float v0 = 0.0f, v1 = 0.0f, v2 = 0.0f;
  const uint32_t fbase = (uint32_t)row * (uint32_t)NNEG;
#pragma unroll
  for (int e = 0; e < 16; ++e) {
    float v = vv[e];
    if (v < 1e30f) {
      float d = v - mu;
      float sc = d * d * inv2s2 + gumbel_at(fbase + (uint32_t)slt[e]);
      if (sc > s2) {
        if (sc > s1) {
          s2 = s1; v2 = v1;
          if (sc > s0) { s1 = s0; v1 = v0; s0 = sc; v0 = v; }
          else         { s1 = sc; v1 = v; }
        } else { s2 = sc; v2 = v; }
      }
    }
  }
  rs[tid * 3 + 0] = s0; rv[tid * 3 + 0] = v0;
  rs[tid * 3 + 1] = s1; rv[tid * 3 + 1] = v1;
  rs[tid * 3 + 2] = s2; rv[tid * 3 + 2] = v2;
  __syncthreads();

  // stage 1: 64 threads each merge 4 threads' entries
  if (tid < 64) {
    float g0 = -FLT_MAX, g1 = -FLT_MAX, g2 = -FLT_MAX;
    float w0 = 0.0f, w1 = 0.0f, w2 = 0.0f;
    for (int blk = 0; blk < 4; ++blk) {
      int b0 = (tid + 64 * blk) * 3;
      for (int e = 0; e < 3; ++e) {
        float sc = rs[b0 + e], v = rv[b0 + e];
        if (sc > g2) {
          if (sc > g1) {
            g2 = g1; w2 = w1;
            if (sc > g0) { g1 = g0; w1 = w0; g0 = sc; w0 = v; }
            else         { g1 = sc; w1 = v; }
          } else { g2 = sc; w2 = v; }
        }
      }
    }
    rs[tid * 3 + 0] = g0; rv[tid * 3 + 0] = w0;
    rs[tid * 3 + 1] = g1; rv[tid * 3 + 1] = w1;
    rs[tid * 3 + 2] = g2; rv[tid * 3 + 2] = w2;
  }
  __syncthreads();

  if (tid == 0) {
    float g0 = -FLT_MAX, g1 = -FLT_MAX, g2 = -FLT_MAX;
    float w0 = 0.0f, w1 = 0.0f, w2 = 0.0f;
    for (int i = 0; i < 192; ++i) {
      float sc = rs[i], v = rv[i];
      if (sc > g2) {
        if (sc > g1) {
          g2 = g1; w2 = w1;
          if (sc > g0) { g1 = g0; w1 = w0; g0 = sc; w0 = v; }
          else         { g1 = sc; w1 = v; }
        } else { g2 = sc; w2 = v; }
      }
    }
    float negmax = fmaxf(w0, fmaxf(w1, w2));
    float neg_loss = 0.04f * (log1pf(expf(50.0f * (w0 - MARGIN))) +
                              log1pf(expf(50.0f * (w1 - MARGIN))) +
                              log1pf(expf(50.0f * (w2 - MARGIN)))) / 3.0f;
    float p0 = sh[0], p1 = sh[1], p2 = sh[2];
    float pos_loss = (log1pf(expf(-2.0f * (p0 - MARGIN))) +
                      log1pf(expf(-2.0f * (p1 - MARGIN))) +
                      log1pf(expf(-2.0f * (p2 - MARGIN)))) / 3.0f;
    atomicAdd(&acc[0], pos_loss + neg_loss);
    if (p2 > negmax + 0.05f) atomicAdd(&acc[1], 1.0f);
    atomicAdd(&acc[2], p0 + p1 + p2);
    atomicAdd(&acc[3], sh[9]);
  }
}

// ---------------------------------------------------------------------------
__global__ void finalize(const float* __restrict__ acc, float* out) {
  if (threadIdx.x == 0 && blockIdx.x == 0) {
    out[0] = acc[0] / 4096.0f;                    // loss
    out[1] = acc[1] / 4096.0f;                    // prec
    out[2] = acc[2] / (4096.0f * 3.0f);           // pos_d
    out[3] = acc[3] / (4096.0f * 4092.0f);        // neg_d
  }
}

extern "C" void kernel_launch(void* const* d_in, const int* in_sizes, int n_in,
                              void* d_out, int out_size, void* d_ws, size_t ws_size,
                              hipStream_t stream) {
  (void)in_sizes; (void)n_in; (void)out_size; (void)ws_size;
  const float* X = (const float*)d_in[0];
  float* S = (float*)d_ws;                                   // 64 MB sim matrix
  float* acc = (float*)((char*)d_ws + (size_t)NN * NN * 4);  // 4 f32 accumulators
  hipMemsetAsync(acc, 0, 4 * sizeof(float), stream);
  dim3 grid(NN / TS, NN / TS);
  gemm_sim<<<grid, 256, 0, stream>>>(X, S);
  row_kernel<<<NN, 256, 0, stream>>>(S, acc);
  finalize<<<1, 64, 0, stream>>>(acc, (float*)d_out);
}

// Round 4
// 422.894 us; speedup vs baseline: 1.7410x; 1.0624x over previous
//
#include <hip/hip_runtime.h>
#include <hip/hip_bf16.h>
#include <cstdint>
#include <cfloat>
#include <math.h>

// Problem constants (fixed by the reference)
#define NN 4096      // rows
#define DD 256       // embedding dim
#define NNEG 4092    // negatives per row
#define MARGIN 0.5f
#define NB 4096      // counting-sort buckets

// ---------------------------------------------------------------------------
// JAX threefry2x32, key = jax.random.key(42) -> (0, 42). Partitionable mode:
// counter (hi=0, lo=i), bits = o0 ^ o1. (verified bit-exact: absmax 0.0 R2/R3)
// ---------------------------------------------------------------------------
__device__ __forceinline__ uint32_t rotl32(uint32_t x, int r) {
  return (x << r) | (x >> (32 - r));
}

__device__ __forceinline__ void threefry2x32_42(uint32_t x0, uint32_t x1,
                                                uint32_t& o0, uint32_t& o1) {
  const uint32_t k0 = 0u, k1 = 42u;
  const uint32_t k2 = k0 ^ k1 ^ 0x1BD11BDAu;
  x0 += k0; x1 += k1;
#define TF_R(r) { x0 += x1; x1 = rotl32(x1, r); x1 ^= x0; }
  TF_R(13) TF_R(15) TF_R(26) TF_R(6)
  x0 += k1; x1 += k2 + 1u;
  TF_R(17) TF_R(29) TF_R(16) TF_R(24)
  x0 += k2; x1 += k0 + 2u;
  TF_R(13) TF_R(15) TF_R(26) TF_R(6)
  x0 += k0; x1 += k1 + 3u;
  TF_R(17) TF_R(29) TF_R(16) TF_R(24)
  x0 += k1; x1 += k2 + 4u;
  TF_R(13) TF_R(15) TF_R(26) TF_R(6)
  x0 += k2; x1 += k0 + 5u;
#undef TF_R
  o0 = x0; o1 = x1;
}

__device__ __forceinline__ float gumbel_at(uint32_t f) {
  uint32_t o0, o1;
  threefry2x32_42(0u, f, o0, o1);
  uint32_t bits = o0 ^ o1;
  uint32_t fb = (bits >> 9) | 0x3F800000u;
  float fl = __uint_as_float(fb) - 1.0f;
  float u = fmaxf(1e-20f, fl + 1e-20f);
  return -logf(-logf(u));
}

__device__ __forceinline__ int bucket_of(float v) {
  return (int)fminf(fmaxf((v + 0.5f) * (float)NB, 0.0f), (float)(NB - 1));
}

// ---------------------------------------------------------------------------
// Symmetric GEMM: S = X * X^T. Upper-triangle 128x128 blocks only; mirror
// written directly (values bit-identical by commutativity of a*b).
// k-accumulation order identical to R2/R3 (kb asc, k+=4, .x.y.z.w) -> sims
// bit-exact vs the validated baseline.
// ---------------------------------------------------------------------------
#define BT 128       // block tile
#define NT (NN / BT) // 32 -> 528 upper-triangle blocks
#define BK 64
#define LDSS 68      // padded LDS row stride (dwords)

__global__ __launch_bounds__(256) void gemm_sim(const float* __restrict__ X,
                                                float* __restrict__ S) {
  __shared__ float As[BT * LDSS];
  __shared__ float Bs[BT * LDSS];
  const int tid = threadIdx.x;
  const int tx = tid & 15, ty = tid >> 4;

  // decode linear upper-triangle index -> (bi, bj), bi <= bj
  int b = blockIdx.x, bi = 0;
  while (b >= NT - bi) { b -= NT - bi; bi++; }
  const int bj = bi + b;
  const int rowBase = bi * BT, colBase = bj * BT;

  float acc[8][8] = {};
  for (int kb = 0; kb < DD; kb += BK) {
#pragma unroll
    for (int it = 0; it < 8; ++it) {
      int idx = tid + 256 * it;            // 2048 float4 slots: 128 rows x 16
      int r = idx >> 4, c4 = idx & 15;
      float4 av = *(const float4*)(X + (size_t)(rowBase + r) * DD + kb + c4 * 4);
      float4 bv = *(const float4*)(X + (size_t)(colBase + r) * DD + kb + c4 * 4);
      *(float4*)(As + r * LDSS + c4 * 4) = av;
      *(float4*)(Bs + r * LDSS + c4 * 4) = bv;
    }
    __syncthreads();
    for (int k = 0; k < BK; k += 4) {
      float4 a[8], bfr[8];
#pragma unroll
      for (int i = 0; i < 8; ++i) a[i] = *(const float4*)(As + (ty + 16 * i) * LDSS + k);
#pragma unroll
      for (int j = 0; j < 8; ++j) bfr[j] = *(const float4*)(Bs + (tx + 16 * j) * LDSS + k);
#pragma unroll
      for (int i = 0; i < 8; ++i)
#pragma unroll
        for (int j = 0; j < 8; ++j) {
          acc[i][j] += a[i].x * bfr[j].x;
          acc[i][j] += a[i].y * bfr[j].y;
          acc[i][j] += a[i].z * bfr[j].z;
          acc[i][j] += a[i].w * bfr[j].w;
        }
    }
    __syncthreads();
  }
  // normal stores (coalesced over tx)
#pragma unroll
  for (int i = 0; i < 8; ++i)
#pragma unroll
    for (int j = 0; j < 8; ++j)
      S[(size_t)(rowBase + ty + 16 * i) * NN + colBase + tx + 16 * j] = acc[i][j];
  // mirror stores (L2 write-combined; skip on diagonal blocks)
  if (bi != bj) {
#pragma unroll
    for (int i = 0; i < 8; ++i)
#pragma unroll
      for (int j = 0; j < 8; ++j)
        S[(size_t)(colBase + tx + 16 * j) * NN + rowBase + ty + 16 * i] = acc[i][j];
  }
}

// ---------------------------------------------------------------------------
// Per-row kernel v3: counting-sort ranks, slot-major rank/score pass.
// One block (256 thr) per row; 16 elements/thread.
// acc[0]=sum losses, acc[1]=prec count, acc[2]=sum pos, acc[3]=sum neg
// ---------------------------------------------------------------------------
__global__ __launch_bounds__(256) void row_kernel(const float* __restrict__ S,
                                                  float* __restrict__ acc) {
  __shared__ uint32_t hist[NB];   // per-bucket counts (preserved)
  __shared__ uint32_t offs[NB];   // excl prefix -> scatter cursor -> bucket end
  __shared__ float sval[NN];      // values scattered by bucket; later rs/rv
  __shared__ float sh[24];        // 0..2 pos sorted, 3 mu, 4 inv2s2, 5..8 wave sums,
                                  // 9 neg sum, 10..13 wave sq sums, 16..19 raw pos
  __shared__ uint32_t wtot[4];    // wave scan totals

  const int row = blockIdx.x;
  const int tid = threadIdx.x;
  const int lane = tid & 63, wid = tid >> 6;

  // zero histogram (16 uints/thread via uint4)
#pragma unroll
  for (int it = 0; it < 4; ++it)
    ((uint4*)hist)[tid + 256 * it] = make_uint4(0u, 0u, 0u, 0u);

  // load 16 elements (coalesced float4), capture positives, poison class block
  const float4* src = (const float4*)(S + (size_t)row * NN);
  const int pslot = row >> 2;
  float vv[16];
#pragma unroll
  for (int it = 0; it < 4; ++it) {
    int slot = tid + 256 * it;
    float4 t4 = src[slot];
    if (slot == pslot) {
      sh[16] = t4.x; sh[17] = t4.y; sh[18] = t4.z; sh[19] = t4.w;
      t4.x = INFINITY; t4.y = INFINITY; t4.z = INFINITY; t4.w = INFINITY;
    }
    vv[4 * it + 0] = t4.x; vv[4 * it + 1] = t4.y;
    vv[4 * it + 2] = t4.z; vv[4 * it + 3] = t4.w;
  }

  // mean partial sums (skip infs)
  float s = 0.0f;
#pragma unroll
  for (int e = 0; e < 16; ++e) if (vv[e] < 1e30f) s += vv[e];
#pragma unroll
  for (int off = 32; off > 0; off >>= 1) s += __shfl_down(s, off, 64);
  if (lane == 0) sh[5 + wid] = s;
  __syncthreads();   // B1: hist zeroed, sh[5..8], sh[16..19] visible

  // histogram
#pragma unroll
  for (int e = 0; e < 16; ++e) atomicAdd(&hist[bucket_of(vv[e])], 1u);

  // tid0: positives sort + mean
  if (tid == 0) {
    int self = row & 3;
    float p[3]; int m = 0;
#pragma unroll
    for (int c = 0; c < 4; ++c)
      if (c != self) p[m++] = sh[16 + c];
    float t;
    if (p[0] > p[1]) { t = p[0]; p[0] = p[1]; p[1] = t; }
    if (p[1] > p[2]) { t = p[1]; p[1] = p[2]; p[2] = t; }
    if (p[0] > p[1]) { t = p[0]; p[0] = p[1]; p[1] = t; }
    sh[0] = p[0]; sh[1] = p[1]; sh[2] = p[2];
    float tot = sh[5] + sh[6] + sh[7] + sh[8];
    sh[9] = tot;
    sh[3] = tot / (float)NNEG;
  }
  __syncthreads();   // B2: hist complete, mu visible

  // block exclusive prefix over NB buckets (16 per thread)
  uint32_t h[16];
  uint32_t s16 = 0;
#pragma unroll
  for (int jj = 0; jj < 4; ++jj) {
    uint4 h4 = ((const uint4*)hist)[tid * 4 + jj];
    h[4 * jj + 0] = h4.x; h[4 * jj + 1] = h4.y;
    h[4 * jj + 2] = h4.z; h[4 * jj + 3] = h4.w;
    s16 += h4.x + h4.y + h4.z + h4.w;
  }
  uint32_t inc = s16;
#pragma unroll
  for (int off = 1; off < 64; off <<= 1) {
    uint32_t n = __shfl_up(inc, (unsigned)off, 64);
    if (lane >= off) inc += n;
  }
  if (lane == 63) wtot[wid] = inc;

  // variance partial sums (two-pass; mu available)
  const float mu = sh[3];
  float q = 0.0f;
#pragma unroll
  for (int e = 0; e < 16; ++e)
    if (vv[e] < 1e30f) { float d = vv[e] - mu; q += d * d; }
#pragma unroll
  for (int off = 32; off > 0; off >>= 1) q += __shfl_down(q, off, 64);
  if (lane == 0) sh[10 + wid] = q;
  __syncthreads();   // B3: wtot, var partials visible

  uint32_t wbase = 0;
  for (int w = 0; w < wid; ++w) wbase += wtot[w];
  uint32_t run = wbase + inc - s16;
#pragma unroll
  for (int jj = 0; jj < 4; ++jj) {
    uint4 o4;
    o4.x = run; run += h[4 * jj + 0];
    o4.y = run; run += h[4 * jj + 1];
    o4.z = run; run += h[4 * jj + 2];
    o4.w = run; run += h[4 * jj + 3];
    ((uint4*)offs)[tid * 4 + jj] = o4;
  }
  if (tid == 0) {
    float var = (sh[10] + sh[11] + sh[12] + sh[13]) / (float)NNEG;
    float sd = sqrtf(var);
    sh[4] = 1.0f / (2.0f * sd * sd);
  }
  __syncthreads();   // B4: offs + sh[4] ready

  // scatter
#pragma unroll
  for (int e = 0; e < 16; ++e) {
    uint32_t sl = atomicAdd(&offs[bucket_of(vv[e])], 1u);
    sval[sl] = vv[e];
  }
  __syncthreads();   // B5: scatter done (offs = bucket ends)

  // rank + score, slot-major: lane L handles slots L+256*it -> consecutive
  // lanes read the same bucket -> broadcast LDS reads, lockstep trips.
  const float inv2s2 = sh[4];
  const uint32_t fbase = (uint32_t)row * (uint32_t)NNEG;
  float s0 = -FLT_MAX, s1 = -FLT_MAX, s2 = -FLT_MAX;
  float v0 = 0.0f, v1 = 0.0f, v2 = 0.0f;
#pragma unroll 1
  for (int it = 0; it < 16; ++it) {
    int sl = tid + 256 * it;
    float v = sval[sl];
    if (v < 1e30f) {
      int bk = bucket_of(v);
      uint32_t end = offs[bk];
      uint32_t st = end - hist[bk];
      int cnt = (int)st;
      for (uint32_t u = st; u < end; ++u) {
        float w = sval[u];
        cnt += (w < v || (w == v && (int)u < sl)) ? 1 : 0;
      }
      float d = v - mu;
      float sc = d * d * inv2s2 + gumbel_at(fbase + (uint32_t)cnt);
      if (sc > s2) {
        if (sc > s1) {
          s2 = s1; v2 = v1;
          if (sc > s0) { s1 = s0; v1 = v0; s0 = sc; v0 = v; }
          else         { s1 = sc; v1 = v; }
        } else { s2 = sc; v2 = v; }
      }
    }
  }
  __syncthreads();   // B6: sval free for reuse

  float* rs = sval;
  float* rv = sval + 768;
  rs[tid * 3 + 0] = s0; rv[tid * 3 + 0] = v0;
  rs[tid * 3 + 1] = s1; rv[tid * 3 + 1] = v1;
  rs[tid * 3 + 2] = s2; rv[tid * 3 + 2] = v2;
  __syncthreads();

  // stage 1: 64 threads each merge 4 threads' entries
  if (tid < 64) {
    float g0 = -FLT_MAX, g1 = -FLT_MAX, g2 = -FLT_MAX;
    float w0 = 0.0f, w1 = 0.0f, w2 = 0.0f;
    for (int blk = 0; blk < 4; ++blk) {
      int b0 = (tid + 64 * blk) * 3;
      for (int e = 0; e < 3; ++e) {
        float sc = rs[b0 + e], v = rv[b0 + e];
        if (sc > g2) {
          if (sc > g1) {
            g2 = g1; w2 = w1;
            if (sc > g0) { g1 = g0; w1 = w0; g0 = sc; w0 = v; }
            else         { g1 = sc; w1 = v; }
          } else { g2 = sc; w2 = v; }
        }
      }
    }
    rs[tid * 3 + 0] = g0; rv[tid * 3 + 0] = w0;
    rs[tid * 3 + 1] = g1; rv[tid * 3 + 1] = w1;
    rs[tid * 3 + 2] = g2; rv[tid * 3 + 2] = w2;
  }
  __syncthreads();

  if (tid == 0) {
    float g0 = -FLT_MAX, g1 = -FLT_MAX, g2 = -FLT_MAX;
    float w0 = 0.0f, w1 = 0.0f, w2 = 0.0f;
    for (int i = 0; i < 192; ++i) {
      float sc = rs[i], v = rv[i];
      if (sc > g2) {
        if (sc > g1) {
          g2 = g1; w2 = w1;
          if (sc > g0) { g1 = g0; w1 = w0; g0 = sc; w0 = v; }
          else         { g1 = sc; w1 = v; }
        } else { g2 = sc; w2 = v; }
      }
    }
    float negmax = fmaxf(w0, fmaxf(w1, w2));
    float neg_loss = 0.04f * (log1pf(expf(50.0f * (w0 - MARGIN))) +
                              log1pf(expf(50.0f * (w1 - MARGIN))) +
                              log1pf(expf(50.0f * (w2 - MARGIN)))) / 3.0f;
    float p0 = sh[0], p1 = sh[1], p2 = sh[2];
    float pos_loss = (log1pf(expf(-2.0f * (p0 - MARGIN))) +
                      log1pf(expf(-2.0f * (p1 - MARGIN))) +
                      log1pf(expf(-2.0f * (p2 - MARGIN)))) / 3.0f;
    atomicAdd(&acc[0], pos_loss + neg_loss);
    if (p2 > negmax + 0.05f) atomicAdd(&acc[1], 1.0f);
    atomicAdd(&acc[2], p0 + p1 + p2);
    atomicAdd(&acc[3], sh[9]);
  }
}

// ---------------------------------------------------------------------------
__global__ void finalize(const float* __restrict__ acc, float* out) {
  if (threadIdx.x == 0 && blockIdx.x == 0) {
    out[0] = acc[0] / 4096.0f;                    // loss
    out[1] = acc[1] / 4096.0f;                    // prec
    out[2] = acc[2] / (4096.0f * 3.0f);           // pos_d
    out[3] = acc[3] / (4096.0f * 4092.0f);        // neg_d
  }
}

extern "C" void kernel_launch(void* const* d_in, const int* in_sizes, int n_in,
                              void* d_out, int out_size, void* d_ws, size_t ws_size,
                              hipStream_t stream) {
  (void)in_sizes; (void)n_in; (void)out_size; (void)ws_size;
  const float* X = (const float*)d_in[0];
  float* S = (float*)d_ws;                                   // 64 MB sim matrix
  float* acc = (float*)((char*)d_ws + (size_t)NN * NN * 4);  // 4 f32 accumulators
  hipMemsetAsync(acc, 0, 4 * sizeof(float), stream);
  gemm_sim<<<NT * (NT + 1) / 2, 256, 0, stream>>>(X, S);
  row_kernel<<<NN, 256, 0, stream>>>(S, acc);
  finalize<<<1, 64, 0, stream>>>(acc, (float*)d_out);
}

// Round 5
// 368.221 us; speedup vs baseline: 1.9995x; 1.1485x over previous
//
#include <hip/hip_runtime.h>
#include <hip/hip_bf16.h>
#include <cstdint>
#include <cfloat>
#include <math.h>

// Problem constants (fixed by the reference)
#define NN 4096      // rows
#define DD 256       // embedding dim
#define NNEG 4092    // negatives per row
#define MARGIN 0.5f
#define NB 3584      // counting-sort buckets (14 per thread; 2 per LDS word)
#define NW (NB / 2)  // packed words

// ---------------------------------------------------------------------------
// JAX threefry2x32, key = jax.random.key(42) -> (0, 42). Partitionable mode:
// counter (hi=0, lo=i), bits = o0 ^ o1. (verified bit-exact: absmax 0.0 R2-R4)
// ---------------------------------------------------------------------------
__device__ __forceinline__ uint32_t rotl32(uint32_t x, int r) {
  return (x << r) | (x >> (32 - r));
}

__device__ __forceinline__ void threefry2x32_42(uint32_t x0, uint32_t x1,
                                                uint32_t& o0, uint32_t& o1) {
  const uint32_t k0 = 0u, k1 = 42u;
  const uint32_t k2 = k0 ^ k1 ^ 0x1BD11BDAu;
  x0 += k0; x1 += k1;
#define TF_R(r) { x0 += x1; x1 = rotl32(x1, r); x1 ^= x0; }
  TF_R(13) TF_R(15) TF_R(26) TF_R(6)
  x0 += k1; x1 += k2 + 1u;
  TF_R(17) TF_R(29) TF_R(16) TF_R(24)
  x0 += k2; x1 += k0 + 2u;
  TF_R(13) TF_R(15) TF_R(26) TF_R(6)
  x0 += k0; x1 += k1 + 3u;
  TF_R(17) TF_R(29) TF_R(16) TF_R(24)
  x0 += k1; x1 += k2 + 4u;
  TF_R(13) TF_R(15) TF_R(26) TF_R(6)
  x0 += k2; x1 += k0 + 5u;
#undef TF_R
  o0 = x0; o1 = x1;
}

__device__ __forceinline__ float gumbel_at(uint32_t f) {
  uint32_t o0, o1;
  threefry2x32_42(0u, f, o0, o1);
  uint32_t bits = o0 ^ o1;
  uint32_t fb = (bits >> 9) | 0x3F800000u;
  float fl = __uint_as_float(fb) - 1.0f;
  float u = fmaxf(1e-20f, fl + 1e-20f);
  return -logf(-logf(u));   // libm logf kept: bit-exact anchor (absmax 0.0)
}

__device__ __forceinline__ int bucket_of(float v) {
  return (int)fminf(fmaxf((v + 0.5f) * (float)NB, 0.0f), (float)(NB - 1));
}

// ---------------------------------------------------------------------------
// Symmetric GEMM: S = X * X^T. Upper-triangle 128x128 blocks, BK=32 so LDS
// = 36.9 KB -> 4 blocks/CU (all 528 blocks co-resident). k-accumulation order
// identical to R2-R4 (k ascending, step 4, .x.y.z.w) -> sims bit-exact.
// ---------------------------------------------------------------------------
#define BT 128
#define NT (NN / BT)   // 32 -> 528 upper-triangle blocks
#define BK 32
#define LDSS 36        // padded LDS row stride (dwords)

__global__ __launch_bounds__(256) void gemm_sim(const float* __restrict__ X,
                                                float* __restrict__ S) {
  __shared__ float As[BT * LDSS];
  __shared__ float Bs[BT * LDSS];
  const int tid = threadIdx.x;
  const int tx = tid & 15, ty = tid >> 4;

  // decode linear upper-triangle index -> (bi, bj), bi <= bj
  int b = blockIdx.x, bi = 0;
  while (b >= NT - bi) { b -= NT - bi; bi++; }
  const int bj = bi + b;
  const int rowBase = bi * BT, colBase = bj * BT;

  float acc[8][8] = {};
  for (int kb = 0; kb < DD; kb += BK) {
#pragma unroll
    for (int it = 0; it < 4; ++it) {
      int idx = tid + 256 * it;            // 1024 float4 slots: 128 rows x 8
      int r = idx >> 3, c4 = idx & 7;
      float4 av = *(const float4*)(X + (size_t)(rowBase + r) * DD + kb + c4 * 4);
      float4 bv = *(const float4*)(X + (size_t)(colBase + r) * DD + kb + c4 * 4);
      *(float4*)(As + r * LDSS + c4 * 4) = av;
      *(float4*)(Bs + r * LDSS + c4 * 4) = bv;
    }
    __syncthreads();
    for (int k = 0; k < BK; k += 4) {
      float4 a[8], bfr[8];
#pragma unroll
      for (int i = 0; i < 8; ++i) a[i] = *(const float4*)(As + (ty + 16 * i) * LDSS + k);
#pragma unroll
      for (int j = 0; j < 8; ++j) bfr[j] = *(const float4*)(Bs + (tx + 16 * j) * LDSS + k);
#pragma unroll
      for (int i = 0; i < 8; ++i)
#pragma unroll
        for (int j = 0; j < 8; ++j) {
          acc[i][j] += a[i].x * bfr[j].x;
          acc[i][j] += a[i].y * bfr[j].y;
          acc[i][j] += a[i].z * bfr[j].z;
          acc[i][j] += a[i].w * bfr[j].w;
        }
    }
    __syncthreads();
  }
#pragma unroll
  for (int i = 0; i < 8; ++i)
#pragma unroll
    for (int j = 0; j < 8; ++j)
      S[(size_t)(rowBase + ty + 16 * i) * NN + colBase + tx + 16 * j] = acc[i][j];
  if (bi != bj) {
#pragma unroll
    for (int i = 0; i < 8; ++i)
#pragma unroll
      for (int j = 0; j < 8; ++j)
        S[(size_t)(colBase + tx + 16 * j) * NN + rowBase + ty + 16 * i] = acc[i][j];
  }
}

// ---------------------------------------------------------------------------
// Per-row kernel v4: packed 16-bit hist/offs (30.9 KB LDS -> 5 blocks/CU),
// shfl butterfly top-3 merge, 6 barriers.
// ---------------------------------------------------------------------------
#define INSERT3(sc, v)                                              \
  if ((sc) > s2) {                                                  \
    if ((sc) > s1) {                                                \
      s2 = s1; v2 = v1;                                             \
      if ((sc) > s0) { s1 = s0; v1 = v0; s0 = (sc); v0 = (v); }     \
      else           { s1 = (sc); v1 = (v); }                       \
    } else { s2 = (sc); v2 = (v); }                                 \
  }

__global__ __launch_bounds__(256) void row_kernel(const float* __restrict__ S,
                                                  float* __restrict__ acc) {
  __shared__ uint32_t histw[NW];  // 2x16-bit counts per word (preserved)
  __shared__ uint32_t offsw[NW];  // 2x16-bit cursors -> bucket ends
  __shared__ float sval[NN];      // values scattered by bucket
  __shared__ float sh[48];        // 0..2 pos sorted, 3 mu, 4 inv2s2,
                                  // 5..8 mean partials, 9 neg sum,
                                  // 10..13 var partials, 16..19 raw pos,
                                  // 24..47 wave top-3 (s,v)x3x4
  __shared__ uint32_t wtot[4];

  const int row = blockIdx.x;
  const int tid = threadIdx.x;
  const int lane = tid & 63, wid = tid >> 6;

  // zero histogram: 7 words/thread, stride 256 -> conflict-free
#pragma unroll
  for (int i = 0; i < 7; ++i) histw[tid + 256 * i] = 0u;

  // load 16 elements (coalesced float4), capture positives, poison class block
  const float4* src = (const float4*)(S + (size_t)row * NN);
  const int pslot = row >> 2;
  float vv[16];
#pragma unroll
  for (int it = 0; it < 4; ++it) {
    int slot = tid + 256 * it;
    float4 t4 = src[slot];
    if (slot == pslot) {
      sh[16] = t4.x; sh[17] = t4.y; sh[18] = t4.z; sh[19] = t4.w;
      t4.x = INFINITY; t4.y = INFINITY; t4.z = INFINITY; t4.w = INFINITY;
    }
    vv[4 * it + 0] = t4.x; vv[4 * it + 1] = t4.y;
    vv[4 * it + 2] = t4.z; vv[4 * it + 3] = t4.w;
  }

  // mean partial sums (skip infs)
  float s = 0.0f;
#pragma unroll
  for (int e = 0; e < 16; ++e) if (vv[e] < 1e30f) s += vv[e];
#pragma unroll
  for (int off = 32; off > 0; off >>= 1) s += __shfl_down(s, off, 64);
  if (lane == 0) sh[5 + wid] = s;
  __syncthreads();   // B1: hist zeroed, mean partials, raw pos visible

  // histogram (packed halves; counts <= 4096 so no carry between halves)
#pragma unroll
  for (int e = 0; e < 16; ++e) {
    int b = bucket_of(vv[e]);
    atomicAdd(&histw[b >> 1], 1u << ((b & 1) << 4));
  }
  if (tid == 0) {
    int self = row & 3;
    float p[3]; int m = 0;
#pragma unroll
    for (int c = 0; c < 4; ++c)
      if (c != self) p[m++] = sh[16 + c];
    float t;
    if (p[0] > p[1]) { t = p[0]; p[0] = p[1]; p[1] = t; }
    if (p[1] > p[2]) { t = p[1]; p[1] = p[2]; p[2] = t; }
    if (p[0] > p[1]) { t = p[0]; p[0] = p[1]; p[1] = t; }
    sh[0] = p[0]; sh[1] = p[1]; sh[2] = p[2];
    float tot = sh[5] + sh[6] + sh[7] + sh[8];
    sh[9] = tot;
    sh[3] = tot / (float)NNEG;
  }
  __syncthreads();   // B2: hist complete, mu visible

  // block exclusive prefix over NB buckets (14 buckets = 7 words per thread)
  uint32_t hw[7];
  uint32_t s14 = 0;
#pragma unroll
  for (int j = 0; j < 7; ++j) {
    hw[j] = histw[7 * tid + j];
    s14 += (hw[j] & 0xFFFFu) + (hw[j] >> 16);
  }
  uint32_t inc = s14;
#pragma unroll
  for (int off = 1; off < 64; off <<= 1) {
    uint32_t n = __shfl_up(inc, (unsigned)off, 64);
    if (lane >= off) inc += n;
  }
  if (lane == 63) wtot[wid] = inc;

  // variance partial sums (two-pass; mu from B2)
  const float mu = sh[3];
  float q = 0.0f;
#pragma unroll
  for (int e = 0; e < 16; ++e)
    if (vv[e] < 1e30f) { float d = vv[e] - mu; q += d * d; }
#pragma unroll
  for (int off = 32; off > 0; off >>= 1) q += __shfl_down(q, off, 64);
  if (lane == 0) sh[10 + wid] = q;
  __syncthreads();   // B3: wtot + var partials visible

  uint32_t wbase = 0;
  for (int w = 0; w < wid; ++w) wbase += wtot[w];
  uint32_t run = wbase + inc - s14;
#pragma unroll
  for (int j = 0; j < 7; ++j) {
    uint32_t lo = run; run += hw[j] & 0xFFFFu;
    uint32_t hi = run; run += hw[j] >> 16;
    offsw[7 * tid + j] = lo | (hi << 16);
  }
  if (tid == 0) {
    float var = (sh[10] + sh[11] + sh[12] + sh[13]) / (float)NNEG;
    float sd = sqrtf(var);
    sh[4] = 1.0f / (2.0f * sd * sd);
  }
  __syncthreads();   // B4: offs + inv2s2 ready

  // scatter
#pragma unroll
  for (int e = 0; e < 16; ++e) {
    int b = bucket_of(vv[e]);
    uint32_t old = atomicAdd(&offsw[b >> 1], 1u << ((b & 1) << 4));
    uint32_t sl = (old >> ((b & 1) << 4)) & 0xFFFFu;
    sval[sl] = vv[e];
  }
  __syncthreads();   // B5: scatter done (offsw = bucket ends)

  // rank + score, slot-major (consecutive lanes -> same/nearby bucket)
  const float inv2s2 = sh[4];
  const uint32_t fbase = (uint32_t)row * (uint32_t)NNEG;
  float s0 = -FLT_MAX, s1 = -FLT_MAX, s2 = -FLT_MAX;
  float v0 = 0.0f, v1 = 0.0f, v2 = 0.0f;
#pragma unroll 1
  for (int it = 0; it < 16; ++it) {
    int sl = tid + 256 * it;
    float v = sval[sl];
    if (v < 1e30f) {
      int b = bucket_of(v);
      uint32_t sh16 = (uint32_t)((b & 1) << 4);
      uint32_t end = (offsw[b >> 1] >> sh16) & 0xFFFFu;
      uint32_t cntb = (histw[b >> 1] >> sh16) & 0xFFFFu;
      uint32_t st = end - cntb;
      int cnt = (int)st;
      for (uint32_t u = st; u < end; ++u) {
        float w = sval[u];
        cnt += (w < v || (w == v && (int)u < sl)) ? 1 : 0;
      }
      float d = v - mu;
      float sc = d * d * inv2s2 + gumbel_at(fbase + (uint32_t)cnt);
      INSERT3(sc, v)
    }
  }

  // wave butterfly top-3 merge (registers only)
#pragma unroll
  for (int dlt = 1; dlt < 64; dlt <<= 1) {
    float t0 = __shfl_xor(s0, dlt, 64), u0 = __shfl_xor(v0, dlt, 64);
    float t1 = __shfl_xor(s1, dlt, 64), u1 = __shfl_xor(v1, dlt, 64);
    float t2 = __shfl_xor(s2, dlt, 64), u2 = __shfl_xor(v2, dlt, 64);
    INSERT3(t0, u0)
    INSERT3(t1, u1)
    INSERT3(t2, u2)
  }
  if (lane == 0) {
    int b0 = 24 + wid * 6;
    sh[b0 + 0] = s0; sh[b0 + 1] = v0;
    sh[b0 + 2] = s1; sh[b0 + 3] = v1;
    sh[b0 + 4] = s2; sh[b0 + 5] = v2;
  }
  __syncthreads();   // B6: wave top-3s in sh

  if (tid == 0) {
    float g0 = -FLT_MAX, g1 = -FLT_MAX, g2 = -FLT_MAX;
    float w0 = 0.0f, w1 = 0.0f, w2 = 0.0f;
    {
      float s0 = g0, s1 = g1, s2 = g2, v0 = w0, v1 = w1, v2 = w2;
#pragma unroll
      for (int i = 0; i < 12; ++i) {
        float sc = sh[24 + 2 * i], v = sh[24 + 2 * i + 1];
        INSERT3(sc, v)
      }
      g0 = s0; g1 = s1; g2 = s2; w0 = v0; w1 = v1; w2 = v2;
    }
    float negmax = fmaxf(w0, fmaxf(w1, w2));
    float neg_loss = 0.04f * (log1pf(expf(50.0f * (w0 - MARGIN))) +
                              log1pf(expf(50.0f * (w1 - MARGIN))) +
                              log1pf(expf(50.0f * (w2 - MARGIN)))) / 3.0f;
    float p0 = sh[0], p1 = sh[1], p2 = sh[2];
    float pos_loss = (log1pf(expf(-2.0f * (p0 - MARGIN))) +
                      log1pf(expf(-2.0f * (p1 - MARGIN))) +
                      log1pf(expf(-2.0f * (p2 - MARGIN)))) / 3.0f;
    atomicAdd(&acc[0], pos_loss + neg_loss);
    if (p2 > negmax + 0.05f) atomicAdd(&acc[1], 1.0f);
    atomicAdd(&acc[2], p0 + p1 + p2);
    atomicAdd(&acc[3], sh[9]);
  }
}

// ---------------------------------------------------------------------------
__global__ void finalize(const float* __restrict__ acc, float* out) {
  if (threadIdx.x == 0 && blockIdx.x == 0) {
    out[0] = acc[0] / 4096.0f;                    // loss
    out[1] = acc[1] / 4096.0f;                    // prec
    out[2] = acc[2] / (4096.0f * 3.0f);           // pos_d
    out[3] = acc[3] / (4096.0f * 4092.0f);        // neg_d
  }
}

extern "C" void kernel_launch(void* const* d_in, const int* in_sizes, int n_in,
                              void* d_out, int out_size, void* d_ws, size_t ws_size,
                              hipStream_t stream) {
  (void)in_sizes; (void)n_in; (void)out_size; (void)ws_size;
  const float* X = (const float*)d_in[0];
  float* S = (float*)d_ws;                                   // 64 MB sim matrix
  float* acc = (float*)((char*)d_ws + (size_t)NN * NN * 4);  // 4 f32 accumulators
  hipMemsetAsync(acc, 0, 4 * sizeof(float), stream);
  gemm_sim<<<NT * (NT + 1) / 2, 256, 0, stream>>>(X, S);
  row_kernel<<<NN, 256, 0, stream>>>(S, acc);
  finalize<<<1, 64, 0, stream>>>(acc, (float*)d_out);
}